// Round 6
// baseline (1087.084 us; speedup 1.0000x reference)
//
#include <hip/hip_runtime.h>

typedef unsigned int u32;
typedef unsigned short u16;

// Problem constants (fixed by the reference)
constexpr int Gn  = 5000;     // genes
constexpr int Bn  = 32;       // batch graphs
constexpr int Pn  = 5000;     // perts
constexpr int Nn  = Bn * Gn;  // 160000
constexpr int ECO = 1600000;
constexpr int EGG = 100000;
constexpr int NTILES = Nn / 128;  // 1250, exact

// ---- workspace layout (float offsets) ----
constexpr int oS1 = 0, oS2 = 128, oS3 = 256, oS4 = 384, oS5 = 640, oSG = 768, oSP1 = 896, oSP2 = 1024;
constexpr int oZERO = 1536;  // stays zero (bias for t1)
constexpr int oA1 = 2048, oB1 = 2112, oA2 = 2176, oB2 = 2240;
constexpr int oA4 = 2304, oB4 = 2432;            // 128 each
constexpr int oA5 = 2560, oB5 = 2624;
constexpr int oAG = 2688, oBG = 2752;
constexpr int oAP1 = 2816, oBP1 = 2880, oAP2 = 2944, oBP2 = 3008;
constexpr int oAvec = 3072, oCvec = 3136, oCcP = 3200;
constexpr int oM  = 4096, oM1 = 8192, oM2 = 12288;
constexpr int oE2 = 16384, oEMB = 18432, oCGRAW = 20480, oCG2 = 22528;
constexpr int oRG  = 24576;
constexpr int oRP  = oRG  + Gn * 64;
constexpr int oQ   = oRP  + Gn * 64;
constexpr int oRGO = oQ   + Gn * 64;
constexpr int oRBG = oRGO + Pn * 64;
constexpr int oAGO = oRBG + Pn * 64;
constexpr int oABG = oAGO + Pn * 64;
constexpr int oM1B = oABG + Pn * 64;
constexpr int oM2B = oM1B + Pn * 64;
constexpr int oDGO = oM2B + Pn * 64;
constexpr int oDBG = oDGO + Pn;
constexpr int oDEG = oDBG + Pn;
constexpr int oW1  = oDEG + Nn;
// bf16 weight copies (u16 elems; offsets in floats)
constexpr int oMBF   = oW1 + Nn;        // 4096 u16 = 2048 f
constexpr int oW11BF = oMBF + 2048;     // 4096 u16
constexpr int oW1BF  = oW11BF + 2048;   // 8192 u16 = 4096 f
constexpr int oW2BF  = oW1BF + 4096;    // 8192 u16
constexpr int oBUF0 = oW2BF + 4096;
constexpr int oBUF1 = oBUF0 + Nn * 64;
constexpr size_t WS_FLOATS = (size_t)oBUF1 + (size_t)Nn * 64;  // ~95 MB

__device__ inline u16 f2bf(float f) {
  u32 u = __float_as_uint(f);
  u = (u + 0x7fffu + ((u >> 16) & 1u)) >> 16;
  return (u16)u;
}
__device__ inline float bflo(u32 v) { return __uint_as_float(v << 16); }
__device__ inline float bfhi(u32 v) { return __uint_as_float(v & 0xffff0000u); }

typedef short s16x8 __attribute__((ext_vector_type(8)));
typedef float f32x4 __attribute__((ext_vector_type(4)));
union U4S8 { uint4 u; s16x8 s; };

__global__ __launch_bounds__(256) void kzero(float* p, int n) {
  int i = blockIdx.x * 256 + threadIdx.x;
  if (i < n) p[i] = 0.f;
}

__global__ __launch_bounds__(256) void kcvt(const float* __restrict__ in, u16* __restrict__ out, int n) {
  int i = blockIdx.x * 256 + threadIdx.x;
  if (i < n) out[i] = f2bf(in[i]);
}

// row-wise L2 renorm (norm clipped to <=1); optional column stats of the output
__global__ __launch_bounds__(256) void krenorm(const float* __restrict__ in, float* __restrict__ out,
                                               float* __restrict__ stats, int rows) {
  int lane = threadIdx.x & 63, wv = threadIdx.x >> 6;
  int gw = blockIdx.x * 4 + wv, nw = gridDim.x * 4;
  float ps = 0.f, pq = 0.f;
  for (int r = gw; r < rows; r += nw) {
    float v = in[r * 64 + lane];
    float sq = v * v;
    for (int off = 32; off; off >>= 1) sq += __shfl_xor(sq, off, 64);
    float nn = sqrtf(sq);
    float s = fminf(1.f, 1.f / fmaxf(nn, 1e-12f));
    float o = v * s;
    out[r * 64 + lane] = o;
    ps += o; pq += o * o;
  }
  if (!stats) return;
  __shared__ float red[4][64], red2[4][64];
  red[wv][lane] = ps; red2[wv][lane] = pq;
  __syncthreads();
  if (wv == 0) {
    float s = red[0][lane] + red[1][lane] + red[2][lane] + red[3][lane];
    float q = red2[0][lane] + red2[1][lane] + red2[2][lane] + red2[3][lane];
    atomicAdd(&stats[lane], s);
    atomicAdd(&stats[64 + lane], q);
  }
}

// finalize BN: a = g*rsqrt(var+eps), b = bt - mean*a
__global__ void kfin(const float* __restrict__ stats, const float* __restrict__ g,
                     const float* __restrict__ bt, float* __restrict__ a, float* __restrict__ b,
                     int cols, float invn) {
  int c = blockIdx.x * 64 + threadIdx.x;
  if (c >= cols) return;
  float mean = stats[c] * invn;
  float var = stats[cols + c] * invn - mean * mean;
  float sc = g[c] * rsqrtf(var + 1e-5f);
  a[c] = sc;
  b[c] = bt[c] - mean * sc;
}

// Mout = alpha * A @ Bm  (64x64 each); optional cvec = bias + beta * A @ (bv1+bv2)
__global__ __launch_bounds__(256) void ksmallmat(const float* __restrict__ A, const float* __restrict__ Bm,
                                                 float alpha, const float* __restrict__ bias,
                                                 const float* __restrict__ bv1, const float* __restrict__ bv2,
                                                 float beta, float* __restrict__ Mout, float* __restrict__ cvec) {
  __shared__ float As[4096], Bs[4096];
  int t = threadIdx.x;
  for (int m = 0; m < 16; m++) { As[m * 256 + t] = A[m * 256 + t]; Bs[m * 256 + t] = Bm[m * 256 + t]; }
  __syncthreads();
  int j = t & 63, ig = t >> 6;
  for (int ii = 0; ii < 16; ii++) {
    int i = ig * 16 + ii;
    float acc = 0.f;
    for (int k = 0; k < 64; k++) acc += As[i * 64 + k] * Bs[k * 64 + j];
    Mout[i * 64 + j] = alpha * acc;
  }
  if (cvec && t < 64) {
    float acc = bias ? bias[t] : 0.f;
    for (int k = 0; k < 64; k++) {
      float bb = (bv1 ? bv1[k] : 0.f) + (bv2 ? bv2[k] : 0.f);
      acc += beta * As[t * 64 + k] * bb;
    }
    cvec[t] = acc;
  }
}

// histogram with ticket: one atomic per edge
__global__ __launch_bounds__(256) void khist(const int* __restrict__ dst, int* __restrict__ cnt,
                                             int* __restrict__ ticket, int E) {
  int e = blockIdx.x * 256 + threadIdx.x;
  if (e < E) ticket[e] = atomicAdd(&cnt[dst[e]], 1);
}

// ---- block scan (1024 elems/block) ----
__global__ __launch_bounds__(256) void kscan1(const int* __restrict__ cnt, int* __restrict__ bsum, int n) {
  __shared__ int sh[256];
  int b = blockIdx.x, t = threadIdx.x;
  int base = b * 1024 + t * 4;
  int s = 0;
#pragma unroll
  for (int j = 0; j < 4; j++) { int i = base + j; if (i < n) s += cnt[i]; }
  sh[t] = s; __syncthreads();
  for (int d = 128; d; d >>= 1) { if (t < d) sh[t] += sh[t + d]; __syncthreads(); }
  if (t == 0) bsum[b] = sh[0];
}
__global__ __launch_bounds__(256) void kscan2(int* bsum, int nb, int* off_n) {
  __shared__ int sh[256];
  int t = threadIdx.x;
  int v = (t < nb) ? bsum[t] : 0;
  sh[t] = v;
  __syncthreads();
  for (int d = 1; d < 256; d <<= 1) {
    int u = (t >= d) ? sh[t - d] : 0;
    __syncthreads();
    sh[t] += u;
    __syncthreads();
  }
  if (t < nb) bsum[t] = sh[t] - v;  // exclusive
  if (t == nb - 1 && off_n) *off_n = sh[t];
}
__global__ __launch_bounds__(256) void kscan3(int* __restrict__ cnt, const int* __restrict__ bsum, int n) {
  __shared__ int sh[256];
  int b = blockIdx.x, t = threadIdx.x;
  int base = b * 1024 + t * 4;
  int c0 = (base + 0 < n) ? cnt[base + 0] : 0;
  int c1 = (base + 1 < n) ? cnt[base + 1] : 0;
  int c2 = (base + 2 < n) ? cnt[base + 2] : 0;
  int c3 = (base + 3 < n) ? cnt[base + 3] : 0;
  int tot = c0 + c1 + c2 + c3;
  sh[t] = tot; __syncthreads();
  for (int d = 1; d < 256; d <<= 1) {
    int v = (t >= d) ? sh[t - d] : 0;
    __syncthreads();
    sh[t] += v;
    __syncthreads();
  }
  int excl = sh[t] - tot + bsum[b];
  if (base + 0 < n) cnt[base + 0] = excl;
  if (base + 1 < n) cnt[base + 1] = excl + c0;
  if (base + 2 < n) cnt[base + 2] = excl + c0 + c1;
  if (base + 3 < n) cnt[base + 3] = excl + c0 + c1 + c2;
}

// atomic-free CSR fill using tickets: pack[off[d]+ticket] = (w, src_full)
__global__ __launch_bounds__(256) void kfillt(const int* __restrict__ src, const int* __restrict__ dst,
                                              const float* __restrict__ w, const int* __restrict__ off,
                                              const int* __restrict__ ticket, float2* __restrict__ pack, int E) {
  int e = blockIdx.x * 256 + threadIdx.x;
  if (e >= E) return;
  int d = dst[e];
  int pos = off[d] + ticket[e];
  pack[pos] = make_float2(w[e], __int_as_float(src[e]));
}

// per-row: deg = 1 + sum(w) over CSR row; dinv = rsqrt(deg)
__global__ __launch_bounds__(256) void kdinvrow(const int* __restrict__ off, const float2* __restrict__ pack,
                                                float* __restrict__ dinv, int n) {
  int i = blockIdx.x * 256 + threadIdx.x;
  if (i >= n) return;
  int b0 = off[i], b1 = off[i + 1];
  float s = 1.f;
  for (int j = b0; j < b1; j++) s += pack[j].x;
  dinv[i] = rsqrtf(s);
}

// wave-per-row CSR gather with cooperative pack load + shuffle broadcast
template <bool OBF>
__global__ __launch_bounds__(256) void kgather(const int* __restrict__ off, const float2* __restrict__ pack,
                                               const float* __restrict__ dinv, const float* __restrict__ tab,
                                               float* __restrict__ aggf, u16* __restrict__ aggb, int n) {
  int lane = threadIdx.x & 63;
  int wv = blockIdx.x * 4 + (threadIdx.x >> 6);
  int nw = gridDim.x * 4;
  for (int i = wv; i < n; i += nw) {
    int b0 = off[i], b1 = off[i + 1];
    float di = dinv[i];
    float acc = di * tab[(i % Gn) * 64 + lane];
    for (int base = b0; base < b1; base += 64) {
      int m = b1 - base; if (m > 64) m = 64;
      float cj = 0.f; int idxj = 0;
      if (lane < m) {
        float2 p = pack[base + lane];
        int s = __float_as_int(p.y);
        cj = p.x * dinv[s];
        idxj = (s % Gn) * 64;
      }
      int j = 0;
      for (; j + 1 < m; j += 2) {
        float c0 = __shfl(cj, j, 64);     int i0 = __shfl(idxj, j, 64);
        float c1 = __shfl(cj, j + 1, 64); int i1 = __shfl(idxj, j + 1, 64);
        acc = fmaf(c0, tab[i0 + lane], acc);
        acc = fmaf(c1, tab[i1 + lane], acc);
      }
      if (j < m) {
        float c0 = __shfl(cj, j, 64); int i0 = __shfl(idxj, j, 64);
        acc = fmaf(c0, tab[i0 + lane], acc);
      }
    }
    acc *= di;
    if (OBF) aggb[(size_t)i * 64 + lane] = f2bf(acc);
    else aggf[(size_t)i * 64 + lane] = acc;
  }
}

// ===================== MFMA bf16 GEMM: Y[N x 64] = pre(X)[N x K] @ Wb^T + bias =====================
// K = KH*32 (X pitch = K bf16, W row length = K). 128-row tiles, 4 waves/block.
// A frags direct from global (each element read once); B frags from L1-resident bf16 weights.
// Epilogue via LDS transpose; BN stats accumulated fp32.
template <int KH, bool PRE, bool EB, bool PERG>
__global__ __launch_bounds__(256, 4) void gemm_mf(
    const u16* __restrict__ Xb, const u16* __restrict__ Wb,
    const float* __restrict__ bias, const float* __restrict__ pa, const float* __restrict__ pb,
    const float* __restrict__ perg, u16* __restrict__ Ybf, int obpitch, int ocoff,
    float* __restrict__ stats, int sqoff) {
  constexpr int K = KH * 32;
  __shared__ float xs[128 * 68];
  __shared__ float sstat[128];
  int t = threadIdx.x;
  int w = t >> 6, lane = t & 63;
  int lr = lane & 15, lk = lane >> 4;   // fragment m/n index, k-chunk
  int cg = t & 7, rg = t >> 3;          // epilogue mapping
  float sS[8], sQ[8];
#pragma unroll
  for (int j = 0; j < 8; j++) { sS[j] = 0.f; sQ[j] = 0.f; }
  float bb[8];
  {
    float4 b0 = *(const float4*)&bias[cg * 8];
    float4 b1 = *(const float4*)&bias[cg * 8 + 4];
    bb[0] = b0.x; bb[1] = b0.y; bb[2] = b0.z; bb[3] = b0.w;
    bb[4] = b1.x; bb[5] = b1.y; bb[6] = b1.z; bb[7] = b1.w;
  }
  for (int tile = blockIdx.x; tile < NTILES; tile += gridDim.x) {
    int R0 = tile * 128;
    int rowbase = R0 + w * 32;
    f32x4 acc[2][4];
#pragma unroll
    for (int tr = 0; tr < 2; tr++)
#pragma unroll
      for (int ct = 0; ct < 4; ct++) acc[tr][ct] = (f32x4){0.f, 0.f, 0.f, 0.f};
#pragma unroll
    for (int kh = 0; kh < KH; kh++) {
      int kb = kh * 32 + lk * 8;
      s16x8 af[2];
#pragma unroll
      for (int tr = 0; tr < 2; tr++) {
        int grow = rowbase + tr * 16 + lr;
        if (PRE) {
          uint4 u = *(const uint4*)&Xb[(size_t)grow * K + kb];
          float4 A0 = *(const float4*)&pa[kb];
          float4 A1 = *(const float4*)&pa[kb + 4];
          const float* pbb = EB ? &pb[(grow / Gn) * 64] : pb;
          float4 B0 = *(const float4*)&pbb[kb];
          float4 B1 = *(const float4*)&pbb[kb + 4];
          float v0 = fmaxf(fmaf(A0.x, bflo(u.x), B0.x), 0.f);
          float v1 = fmaxf(fmaf(A0.y, bfhi(u.x), B0.y), 0.f);
          float v2 = fmaxf(fmaf(A0.z, bflo(u.y), B0.z), 0.f);
          float v3 = fmaxf(fmaf(A0.w, bfhi(u.y), B0.w), 0.f);
          float v4 = fmaxf(fmaf(A1.x, bflo(u.z), B1.x), 0.f);
          float v5 = fmaxf(fmaf(A1.y, bfhi(u.z), B1.y), 0.f);
          float v6 = fmaxf(fmaf(A1.z, bflo(u.w), B1.z), 0.f);
          float v7 = fmaxf(fmaf(A1.w, bfhi(u.w), B1.w), 0.f);
          U4S8 c;
          c.u.x = (u32)f2bf(v0) | ((u32)f2bf(v1) << 16);
          c.u.y = (u32)f2bf(v2) | ((u32)f2bf(v3) << 16);
          c.u.z = (u32)f2bf(v4) | ((u32)f2bf(v5) << 16);
          c.u.w = (u32)f2bf(v6) | ((u32)f2bf(v7) << 16);
          af[tr] = c.s;
        } else {
          af[tr] = *(const s16x8*)&Xb[(size_t)grow * K + kb];
        }
      }
#pragma unroll
      for (int ct = 0; ct < 4; ct++) {
        s16x8 bfr = *(const s16x8*)&Wb[(ct * 16 + lr) * K + kb];
#pragma unroll
        for (int tr = 0; tr < 2; tr++)
          acc[tr][ct] = __builtin_amdgcn_mfma_f32_16x16x32_bf16(af[tr], bfr, acc[tr][ct], 0, 0, 0);
      }
    }
    __syncthreads();  // previous tile's readback complete
    // C layout: col = lane&15, row = (lane>>4)*4 + reg  [m89]
#pragma unroll
    for (int tr = 0; tr < 2; tr++)
#pragma unroll
      for (int ct = 0; ct < 4; ct++)
#pragma unroll
        for (int r = 0; r < 4; r++)
          xs[(w * 32 + tr * 16 + lk * 4 + r) * 68 + ct * 16 + lr] = acc[tr][ct][r];
    __syncthreads();
    // epilogue: coalesced readback, bias/perg, stats, bf16 store
#pragma unroll
    for (int i = 0; i < 4; i++) {
      int lrow = rg * 4 + i;
      int grow = R0 + lrow;
      float4 x0 = *(const float4*)&xs[lrow * 68 + cg * 8];
      float4 x1 = *(const float4*)&xs[lrow * 68 + cg * 8 + 4];
      float v[8] = {x0.x, x0.y, x0.z, x0.w, x1.x, x1.y, x1.z, x1.w};
#pragma unroll
      for (int j = 0; j < 8; j++) v[j] += bb[j];
      if (PERG) {
        int qr = grow % Gn;
        float4 q0 = *(const float4*)&perg[(size_t)qr * 64 + cg * 8];
        float4 q1 = *(const float4*)&perg[(size_t)qr * 64 + cg * 8 + 4];
        v[0] += q0.x; v[1] += q0.y; v[2] += q0.z; v[3] += q0.w;
        v[4] += q1.x; v[5] += q1.y; v[6] += q1.z; v[7] += q1.w;
      }
#pragma unroll
      for (int j = 0; j < 8; j++) { sS[j] += v[j]; sQ[j] += v[j] * v[j]; }
      uint4 o;
      o.x = (u32)f2bf(v[0]) | ((u32)f2bf(v[1]) << 16);
      o.y = (u32)f2bf(v[2]) | ((u32)f2bf(v[3]) << 16);
      o.z = (u32)f2bf(v[4]) | ((u32)f2bf(v[5]) << 16);
      o.w = (u32)f2bf(v[6]) | ((u32)f2bf(v[7]) << 16);
      *(uint4*)&Ybf[(size_t)grow * obpitch + ocoff + cg * 8] = o;
    }
  }
  __syncthreads();
  for (int idx = t; idx < 128; idx += 256) sstat[idx] = 0.f;
  __syncthreads();
#pragma unroll
  for (int j = 0; j < 8; j++) {
    atomicAdd(&sstat[cg * 8 + j], sS[j]);
    atomicAdd(&sstat[64 + cg * 8 + j], sQ[j]);
  }
  __syncthreads();
  for (int idx = t; idx < 64; idx += 256) {
    atomicAdd(&stats[idx], sstat[idx]);
    atomicAdd(&stats[sqoff + idx], sstat[64 + idx]);
  }
}

// ===================== small GEMM (Pn/Gn paths, fp32) =====================
template <bool TWO, bool PRE, bool PRELU, bool PERG, bool STATS>
__global__ __launch_bounds__(256) void gemm64k(
    const float* __restrict__ X, const float* __restrict__ Xb,
    const float* __restrict__ Wm, const float* __restrict__ Wb,
    const float* __restrict__ bias,
    const float* __restrict__ pa, const float* __restrict__ pb,
    const float* __restrict__ perg, int tabrows,
    float* __restrict__ Y, float* __restrict__ stats, int rows) {
  __shared__ float xs[4096];
  __shared__ float red[4][64], red2[4][64];
  int t = threadIdx.x, lane = t & 63, wv = t >> 6;
  int ntiles = (rows + 63) >> 6;
  float psum = 0.f, psq = 0.f;
  float bv = bias ? bias[lane] : 0.f;
  for (int tile = blockIdx.x; tile < ntiles; tile += gridDim.x) {
    int base = tile * 64;
    float acc[16];
#pragma unroll
    for (int j = 0; j < 16; j++) acc[j] = bv;
    for (int pass = 0; pass < (TWO ? 2 : 1); pass++) {
      const float* Xp = pass ? Xb : X;
      const float* Wp = pass ? Wb : Wm;
      __syncthreads();
#pragma unroll
      for (int m = 0; m < 16; m++) {
        int fl = m * 256 + t;
        int r = fl >> 6, c = fl & 63;
        int gr = base + r;
        float v = (gr < rows) ? Xp[gr * 64 + c] : 0.f;
        if (PRE) { v = pa[c] * v + pb[c]; if (PRELU) v = fmaxf(v, 0.f); }
        xs[fl] = v;
      }
      __syncthreads();
      float Wreg[64];
#pragma unroll
      for (int k = 0; k < 64; k++) Wreg[k] = Wp[lane * 64 + k];
#pragma unroll
      for (int j = 0; j < 16; j++) {
        int r = wv * 16 + j;
        const float4* xr = (const float4*)&xs[r * 64];
        float a = acc[j];
#pragma unroll
        for (int kk = 0; kk < 16; kk++) {
          float4 xv = xr[kk];
          a = fmaf(xv.x, Wreg[4 * kk + 0], a);
          a = fmaf(xv.y, Wreg[4 * kk + 1], a);
          a = fmaf(xv.z, Wreg[4 * kk + 2], a);
          a = fmaf(xv.w, Wreg[4 * kk + 3], a);
        }
        acc[j] = a;
      }
    }
#pragma unroll
    for (int j = 0; j < 16; j++) {
      int gr = base + wv * 16 + j;
      if (gr < rows) {
        float v = acc[j];
        if (PERG) v += perg[(gr % tabrows) * 64 + lane];
        Y[gr * 64 + lane] = v;
        if (STATS) { psum += v; psq += v * v; }
      }
    }
  }
  if (STATS) {
    __syncthreads();
    red[wv][lane] = psum; red2[wv][lane] = psq;
    __syncthreads();
    if (wv == 0) {
      float s = red[0][lane] + red[1][lane] + red[2][lane] + red[3][lane];
      float q = red2[0][lane] + red2[1][lane] + red2[2][lane] + red2[3][lane];
      atomicAdd(&stats[lane], s);
      atomicAdd(&stats[64 + lane], q);
    }
  }
}

// stats of u = a2*T2(bf16) + b2 + emb[row/G]  (no store)
__global__ __launch_bounds__(256) void k7_kernel(const u16* __restrict__ T2, const float* __restrict__ a2,
                                                 const float* __restrict__ b2, const float* __restrict__ emb,
                                                 float* __restrict__ stats) {
  __shared__ float sstat[128];
  int t = threadIdx.x, cg = t & 7;
  float sS[8], sQ[8];
#pragma unroll
  for (int j = 0; j < 8; j++) { sS[j] = 0.f; sQ[j] = 0.f; }
  int c8 = cg * 8;
  float4 A0 = *(const float4*)&a2[c8];
  float4 A1 = *(const float4*)&a2[c8 + 4];
  float4 B0 = *(const float4*)&b2[c8];
  float4 B1 = *(const float4*)&b2[c8 + 4];
  int total8 = Nn * 8;
  int stride = gridDim.x * 256;
  for (int g8 = blockIdx.x * 256 + t; g8 < total8; g8 += stride) {
    int i = g8 >> 3;
    int b = i / Gn;
    uint4 u = *(const uint4*)&T2[(size_t)i * 64 + c8];
    float4 E0 = *(const float4*)&emb[b * 64 + c8];
    float4 E1 = *(const float4*)&emb[b * 64 + c8 + 4];
    float v[8];
    v[0] = fmaf(A0.x, bflo(u.x), B0.x) + E0.x;
    v[1] = fmaf(A0.y, bfhi(u.x), B0.y) + E0.y;
    v[2] = fmaf(A0.z, bflo(u.y), B0.z) + E0.z;
    v[3] = fmaf(A0.w, bfhi(u.y), B0.w) + E0.w;
    v[4] = fmaf(A1.x, bflo(u.z), B1.x) + E1.x;
    v[5] = fmaf(A1.y, bfhi(u.z), B1.y) + E1.y;
    v[6] = fmaf(A1.z, bflo(u.w), B1.z) + E1.z;
    v[7] = fmaf(A1.w, bfhi(u.w), B1.w) + E1.w;
#pragma unroll
    for (int j = 0; j < 8; j++) { sS[j] += v[j]; sQ[j] += v[j] * v[j]; }
  }
  for (int idx = t; idx < 128; idx += 256) sstat[idx] = 0.f;
  __syncthreads();
#pragma unroll
  for (int j = 0; j < 8; j++) {
    atomicAdd(&sstat[c8 + j], sS[j]);
    atomicAdd(&sstat[64 + c8 + j], sQ[j]);
  }
  __syncthreads();
  for (int idx = t; idx < 64; idx += 256) {
    atomicAdd(&stats[idx], sstat[idx]);
    atomicAdd(&stats[64 + idx], sstat[64 + idx]);
  }
}

// finalize S3 and build folded vectors: Avec = a3*a2, e2[b] = a3*(b2+emb[b]) + b3
__global__ __launch_bounds__(256) void kfinS3e2(const float* __restrict__ stats, const float* __restrict__ g,
                                                const float* __restrict__ bt, const float* __restrict__ a2,
                                                const float* __restrict__ b2, const float* __restrict__ emb,
                                                float* __restrict__ Avec, float* __restrict__ e2, float invn) {
  __shared__ float a3s[64], b3s[64];
  int t = threadIdx.x;
  if (t < 64) {
    float mean = stats[t] * invn;
    float var = stats[64 + t] * invn - mean * mean;
    float sc = g[t] * rsqrtf(var + 1e-5f);
    float sh = bt[t] - mean * sc;
    a3s[t] = sc; b3s[t] = sh;
    Avec[t] = sc * a2[t];
  }
  __syncthreads();
  for (int idx = t; idx < 2048; idx += 256) {
    int c = idx & 63;
    e2[idx] = a3s[c] * (b2[c] + emb[idx]) + b3s[c];
  }
}

// w1[i] = dot(a5*R2(bf16)+b5, indv_w1[i%G]) + indv_b1[i%G]
__global__ __launch_bounds__(256) void k13_kernel(const u16* __restrict__ R2, const float* __restrict__ a5,
                                                  const float* __restrict__ b5, const float* __restrict__ iw1,
                                                  const float* __restrict__ ib1, float* __restrict__ w1out,
                                                  int rows) {
  int t = blockIdx.x * 256 + threadIdx.x;
  int i = t >> 4, j = t & 15;
  if (i >= rows) return;
  int g = i % Gn;
  uint2 u = *(const uint2*)&R2[(size_t)i * 64 + j * 4];
  float rx = bflo(u.x), ry = bfhi(u.x), rz = bflo(u.y), rw = bfhi(u.y);
  float4 a = ((const float4*)a5)[j];
  float4 b = ((const float4*)b5)[j];
  float4 w = ((const float4*)iw1)[g * 16 + j];
  float p = (a.x * rx + b.x) * w.x + (a.y * ry + b.y) * w.y +
            (a.z * rz + b.z) * w.z + (a.w * rw + b.w) * w.w;
  for (int off = 8; off; off >>= 1) p += __shfl_xor(p, off, 64);
  if (j == 0) w1out[i] = p + ib1[g];
}

// init cgraw with bias
__global__ __launch_bounds__(256) void kinitcg(const float* __restrict__ cgb1, float* __restrict__ cgraw) {
  int idx = blockIdx.x * 256 + threadIdx.x;
  if (idx < Bn * 64) cgraw[idx] = cgb1[idx & 63];
}

// split-K GEMM: cgraw[b][col] += sum_{k in chunk} w1[b][k]*cgW1[col][k]
__global__ __launch_bounds__(256) void kcg1s(const float* __restrict__ w1, const float* __restrict__ cgW1,
                                             float* __restrict__ cgraw) {
  __shared__ float w1s[64 * 36];
  __shared__ float cgs[64 * 65];
  int t = threadIdx.x;
  int k0 = blockIdx.x * 64;
  int kmax = Gn - k0; if (kmax > 64) kmax = 64;
  for (int idx = t; idx < 2048; idx += 256) {
    int row = idx >> 6, k = idx & 63;
    w1s[k * 36 + row] = (k < kmax) ? w1[row * Gn + k0 + k] : 0.f;
  }
  for (int idx = t; idx < 4096; idx += 256) {
    int col = idx >> 6, k = idx & 63;
    cgs[k * 65 + col] = (k < kmax) ? cgW1[col * Gn + k0 + k] : 0.f;
  }
  __syncthreads();
  int col = t & 63, rg = t >> 6;
  float acc[8];
#pragma unroll
  for (int i = 0; i < 8; i++) acc[i] = 0.f;
  for (int k = 0; k < 64; k++) {
    float wk = cgs[k * 65 + col];
    const float* wr = &w1s[k * 36 + rg * 8];
    float4 r0 = *(const float4*)wr;
    float4 r1 = *(const float4*)(wr + 4);
    acc[0] = fmaf(r0.x, wk, acc[0]);
    acc[1] = fmaf(r0.y, wk, acc[1]);
    acc[2] = fmaf(r0.z, wk, acc[2]);
    acc[3] = fmaf(r0.w, wk, acc[3]);
    acc[4] = fmaf(r1.x, wk, acc[4]);
    acc[5] = fmaf(r1.y, wk, acc[5]);
    acc[6] = fmaf(r1.z, wk, acc[6]);
    acc[7] = fmaf(r1.w, wk, acc[7]);
  }
#pragma unroll
  for (int i = 0; i < 8; i++) atomicAdd(&cgraw[(rg * 8 + i) * 64 + col], acc[i]);
}

// single-block: cg2 = bn2(relu(bn1(cgraw)) @ W2^T + b2)   (BN over 32 rows)
__global__ __launch_bounds__(256) void kcg2(const float* __restrict__ cgraw, const float* __restrict__ g1,
                                            const float* __restrict__ bt1, const float* __restrict__ W2,
                                            const float* __restrict__ b2, const float* __restrict__ g2,
                                            const float* __restrict__ bt2, float* __restrict__ cg2out) {
  int t = threadIdx.x, c = t & 63, bg = t >> 6;
  __shared__ float hmid[2048], sred[4][64], qred[4][64], asc[64], bsh[64];
  float y[8];
  float ps = 0.f, pq = 0.f;
  for (int jb = 0; jb < 8; jb++) {
    int b = bg * 8 + jb;
    float v = cgraw[b * 64 + c];
    y[jb] = v; ps += v; pq += v * v;
  }
  sred[bg][c] = ps; qred[bg][c] = pq;
  __syncthreads();
  if (t < 64) {
    float s = sred[0][t] + sred[1][t] + sred[2][t] + sred[3][t];
    float q = qred[0][t] + qred[1][t] + qred[2][t] + qred[3][t];
    float mean = s * (1.f / 32.f), var = q * (1.f / 32.f) - mean * mean;
    float sc = g1[t] * rsqrtf(var + 1e-5f);
    asc[t] = sc; bsh[t] = bt1[t] - mean * sc;
  }
  __syncthreads();
  for (int jb = 0; jb < 8; jb++) { int b = bg * 8 + jb; hmid[b * 64 + c] = fmaxf(asc[c] * y[jb] + bsh[c], 0.f); }
  __syncthreads();
  ps = 0.f; pq = 0.f;
  for (int jb = 0; jb < 8; jb++) {
    int b = bg * 8 + jb;
    float a = b2[c];
    for (int k = 0; k < 64; k++) a += hmid[b * 64 + k] * W2[c * 64 + k];
    y[jb] = a; ps += a; pq += a * a;
  }
  sred[bg][c] = ps; qred[bg][c] = pq;
  __syncthreads();
  if (t < 64) {
    float s = sred[0][t] + sred[1][t] + sred[2][t] + sred[3][t];
    float q = qred[0][t] + qred[1][t] + qred[2][t] + qred[3][t];
    float mean = s * (1.f / 32.f), var = q * (1.f / 32.f) - mean * mean;
    float sc = g2[t] * rsqrtf(var + 1e-5f);
    asc[t] = sc; bsh[t] = bt2[t] - mean * sc;
  }
  __syncthreads();
  for (int jb = 0; jb < 8; jb++) { int b = bg * 8 + jb; cg2out[b * 64 + c] = asc[c] * y[jb] + bsh[c]; }
}

// single-block: emb = mlp3(pglob[pert_idx]) with BN over 32 rows
__global__ __launch_bounds__(256) void kemb(const float* __restrict__ m2, const float* __restrict__ aP2,
                                            const float* __restrict__ bP2, const int* __restrict__ pidx,
                                            const float* __restrict__ Wm, const float* __restrict__ bv,
                                            const float* __restrict__ gg, const float* __restrict__ btv,
                                            float* __restrict__ emb) {
  int t = threadIdx.x, c = t & 63, bg = t >> 6;
  __shared__ float xin[2048], hmid[2048], sred[4][64], qred[4][64], asc[64], bsh[64];
  for (int idx = t; idx < 2048; idx += 256) {
    int b = idx >> 6, cc = idx & 63;
    xin[idx] = aP2[cc] * m2[pidx[b] * 64 + cc] + bP2[cc];
  }
  __syncthreads();
  float y[8];
  float ps = 0.f, pq = 0.f;
  for (int jb = 0; jb < 8; jb++) {
    int b = bg * 8 + jb;
    float a = bv[c];
    for (int k = 0; k < 64; k++) a += xin[b * 64 + k] * Wm[c * 64 + k];
    y[jb] = a; ps += a; pq += a * a;
  }
  sred[bg][c] = ps; qred[bg][c] = pq;
  __syncthreads();
  if (t < 64) {
    float s = sred[0][t] + sred[1][t] + sred[2][t] + sred[3][t];
    float q = qred[0][t] + qred[1][t] + qred[2][t] + qred[3][t];
    float mean = s * (1.f / 32.f), var = q * (1.f / 32.f) - mean * mean;
    float sc = gg[t] * rsqrtf(var + 1e-5f);
    asc[t] = sc; bsh[t] = btv[t] - mean * sc;
  }
  __syncthreads();
  for (int jb = 0; jb < 8; jb++) { int b = bg * 8 + jb; hmid[b * 64 + c] = fmaxf(asc[c] * y[jb] + bsh[c], 0.f); }
  __syncthreads();
  ps = 0.f; pq = 0.f;
  for (int jb = 0; jb < 8; jb++) {
    int b = bg * 8 + jb;
    float a = bv[64 + c];
    for (int k = 0; k < 64; k++) a += hmid[b * 64 + k] * Wm[4096 + c * 64 + k];
    y[jb] = a; ps += a; pq += a * a;
  }
  sred[bg][c] = ps; qred[bg][c] = pq;
  __syncthreads();
  if (t < 64) {
    float s = sred[0][t] + sred[1][t] + sred[2][t] + sred[3][t];
    float q = qred[0][t] + qred[1][t] + qred[2][t] + qred[3][t];
    float mean = s * (1.f / 32.f), var = q * (1.f / 32.f) - mean * mean;
    float sc = gg[64 + t] * rsqrtf(var + 1e-5f);
    asc[t] = sc; bsh[t] = btv[64 + t] - mean * sc;
  }
  __syncthreads();
  for (int jb = 0; jb < 8; jb++) { int b = bg * 8 + jb; emb[b * 64 + c] = asc[c] * y[jb] + bsh[c]; }
}

// final: out[b][g] = w1*iw2[g][0] + dot(cg2[b], iw2[g][1:65]) + ib2[g] + x[b][g]
__global__ __launch_bounds__(256) void kfinal(const float* __restrict__ w1, const float* __restrict__ cg2,
                                              const float* __restrict__ iw2, const float* __restrict__ ib2,
                                              const float* __restrict__ x, float* __restrict__ out) {
  __shared__ float iws[64 * 65], cgs[2048];
  int t = threadIdx.x;
  int g0 = blockIdx.x * 64;
  for (int idx = t; idx < 64 * 65; idx += 256) {
    int gi = g0 * 65 + idx;
    iws[idx] = (gi < Gn * 65) ? iw2[gi] : 0.f;
  }
  for (int idx = t; idx < 2048; idx += 256) cgs[idx] = cg2[idx];
  __syncthreads();
  int gl = t & 63, bg = t >> 6;
  int g = g0 + gl;
  if (g >= Gn) return;
  float bias = ib2[g];
  for (int jb = 0; jb < 8; jb++) {
    int b = bg * 8 + jb;
    float acc = w1[b * Gn + g] * iws[gl * 65] + bias;
    for (int k = 0; k < 64; k++) acc += cgs[b * 64 + k] * iws[gl * 65 + 1 + k];
    out[b * Gn + g] = acc + x[b * Gn + g];
  }
}

extern "C" void kernel_launch(void* const* d_in, const int* in_sizes, int n_in,
                              void* d_out, int out_size, void* d_ws, size_t ws_size,
                              hipStream_t stream) {
  (void)in_sizes; (void)n_in; (void)out_size;
  if (ws_size < WS_FLOATS * sizeof(float)) return;

  const float* x        = (const float*)d_in[0];
  const int*   pert_idx = (const int*)d_in[1];
  const int*   ei_co    = (const int*)d_in[2];
  const float* w_co     = (const float*)d_in[3];
  const int*   ei_go    = (const int*)d_in[4];
  const float* w_go     = (const float*)d_in[5];
  const int*   ei_bg    = (const int*)d_in[6];
  const float* w_bg     = (const float*)d_in[7];
  const float* gene_tab = (const float*)d_in[8];
  const float* pos_tab  = (const float*)d_in[9];
  const float* go_tab   = (const float*)d_in[10];
  const float* bg_tab   = (const float*)d_in[11];
  const float* bn_g     = (const float*)d_in[12];
  const float* bn_b     = (const float*)d_in[13];
  const float* sg_W     = (const float*)d_in[14];
  const float* sg_b     = (const float*)d_in[15];
  const float* mlp_W    = (const float*)d_in[16];
  const float* mlp_b    = (const float*)d_in[17];
  const float* mlp_g    = (const float*)d_in[18];
  const float* mlp_bt   = (const float*)d_in[19];
  const float* rec_W1   = (const float*)d_in[20];
  const float* rec_b1   = (const float*)d_in[21];
  const float* rec_g1   = (const float*)d_in[22];
  const float* rec_bt1  = (const float*)d_in[23];
  const float* rec_W2   = (const float*)d_in[24];
  const float* rec_b2   = (const float*)d_in[25];
  const float* rec_g2   = (const float*)d_in[26];
  const float* rec_bt2  = (const float*)d_in[27];
  const float* indv_w1  = (const float*)d_in[28];
  const float* indv_b1  = (const float*)d_in[29];
  const float* cg_W1    = (const float*)d_in[30];
  const float* cg_b1    = (const float*)d_in[31];
  const float* cg_g1    = (const float*)d_in[32];
  const float* cg_bt1   = (const float*)d_in[33];
  const float* cg_W2    = (const float*)d_in[34];
  const float* cg_b2    = (const float*)d_in[35];
  const float* cg_g2    = (const float*)d_in[36];
  const float* cg_bt2   = (const float*)d_in[37];
  const float* indv_w2  = (const float*)d_in[38];
  const float* indv_b2  = (const float*)d_in[39];

  float* W = (float*)d_ws;
  float* buf0 = W + oBUF0;
  float* buf1 = W + oBUF1;
  u16* Mbf   = (u16*)(W + oMBF);
  u16* W11bf = (u16*)(W + oW11BF);
  u16* W1bf  = (u16*)(W + oW1BF);
  u16* W2bf  = (u16*)(W + oW2BF);

  // CSR scratch lives in buf1 (consumed before t1 writes buf1)
  int*    co_cnt    = (int*)(buf1);
  int*    sbsum     = (int*)(buf1 + 320128);
  float2* co_pack   = (float2*)(buf1 + 400000);
  int*    go_cnt    = (int*)(buf1 + 3700000);
  float2* go_pack   = (float2*)(buf1 + 3720000);
  int*    bg_cnt    = (int*)(buf1 + 4000000);
  float2* bg_pack   = (float2*)(buf1 + 4020000);
  int*    co_ticket = (int*)(buf1 + 4500000);
  int*    go_ticket = (int*)(buf1 + 6200000);
  int*    bg_ticket = (int*)(buf1 + 6400000);

  // --- phase 0: zero stats, renorm tables, fold small matrices, bf16 weights ---
  kzero<<<8, 256, 0, stream>>>(W, 2048);
  kcvt<<<16, 256, 0, stream>>>(mlp_W + 12288, W11bf, 4096);
  kcvt<<<32, 256, 0, stream>>>(rec_W1, W1bf, 8192);
  kcvt<<<32, 256, 0, stream>>>(rec_W2, W2bf, 8192);
  krenorm<<<160, 256, 0, stream>>>(gene_tab, W + oRG, W + oSG, Gn);
  krenorm<<<160, 256, 0, stream>>>(pos_tab, W + oRP, nullptr, Gn);
  krenorm<<<160, 256, 0, stream>>>(go_tab, W + oRGO, nullptr, Pn);
  krenorm<<<160, 256, 0, stream>>>(bg_tab, W + oRBG, nullptr, Pn);
  kfin<<<1, 64, 0, stream>>>(W + oSG, bn_g, bn_b, W + oAG, W + oBG, 64, 1.f / Gn);
  ksmallmat<<<1, 256, 0, stream>>>(mlp_W + 8192, sg_W, 0.2f, mlp_b + 128, sg_b, nullptr, 0.2f, W + oM, W + oCvec);
  kcvt<<<16, 256, 0, stream>>>(W + oM, Mbf, 4096);
  ksmallmat<<<1, 256, 0, stream>>>(mlp_W, sg_W + 4096, 1.f, nullptr, nullptr, nullptr, 0.f, W + oM1, nullptr);
  ksmallmat<<<1, 256, 0, stream>>>(mlp_W, sg_W + 8192, 1.f, mlp_b, sg_b + 64, sg_b + 128, 1.f, W + oM2, W + oCcP);
  gemm64k<false, true, true, false, false><<<79, 256, 0, stream>>>(
      W + oRG, nullptr, mlp_W + 8192, nullptr, W + oCvec, W + oAG, W + oBG, nullptr, 0, W + oQ, nullptr, Gn);

  // --- co graph: ticket CSR build + gather (bf16 out) ---
  kzero<<<(160001 + 255) / 256, 256, 0, stream>>>((float*)co_cnt, 160001);
  khist<<<(ECO + 255) / 256, 256, 0, stream>>>(ei_co + ECO, co_cnt, co_ticket, ECO);
  kscan1<<<157, 256, 0, stream>>>(co_cnt, sbsum, Nn);
  kscan2<<<1, 256, 0, stream>>>(sbsum, 157, co_cnt + Nn);
  kscan3<<<157, 256, 0, stream>>>(co_cnt, sbsum, Nn);
  kfillt<<<(ECO + 255) / 256, 256, 0, stream>>>(ei_co, ei_co + ECO, w_co, co_cnt, co_ticket, co_pack, ECO);
  kdinvrow<<<(Nn + 255) / 256, 256, 0, stream>>>(co_cnt, co_pack, W + oDEG, Nn);
  kgather<true><<<2048, 256, 0, stream>>>(co_cnt, co_pack, W + oDEG, W + oRP, nullptr, (u16*)buf0, Nn);

  // --- go graph ---
  kzero<<<(5001 + 255) / 256, 256, 0, stream>>>((float*)go_cnt, 5001);
  khist<<<(EGG + 255) / 256, 256, 0, stream>>>(ei_go + EGG, go_cnt, go_ticket, EGG);
  kscan1<<<5, 256, 0, stream>>>(go_cnt, sbsum, Pn);
  kscan2<<<1, 256, 0, stream>>>(sbsum, 5, go_cnt + Pn);
  kscan3<<<5, 256, 0, stream>>>(go_cnt, sbsum, Pn);
  kfillt<<<(EGG + 255) / 256, 256, 0, stream>>>(ei_go, ei_go + EGG, w_go, go_cnt, go_ticket, go_pack, EGG);
  kdinvrow<<<(Pn + 255) / 256, 256, 0, stream>>>(go_cnt, go_pack, W + oDGO, Pn);
  kgather<false><<<512, 256, 0, stream>>>(go_cnt, go_pack, W + oDGO, W + oRGO, W + oAGO, nullptr, Pn);

  // --- bg graph ---
  kzero<<<(5001 + 255) / 256, 256, 0, stream>>>((float*)bg_cnt, 5001);
  khist<<<(EGG + 255) / 256, 256, 0, stream>>>(ei_bg + EGG, bg_cnt, bg_ticket, EGG);
  kscan1<<<5, 256, 0, stream>>>(bg_cnt, sbsum, Pn);
  kscan2<<<1, 256, 0, stream>>>(sbsum, 5, bg_cnt + Pn);
  kscan3<<<5, 256, 0, stream>>>(bg_cnt, sbsum, Pn);
  kfillt<<<(EGG + 255) / 256, 256, 0, stream>>>(ei_bg, ei_bg + EGG, w_bg, bg_cnt, bg_ticket, bg_pack, EGG);
  kdinvrow<<<(Pn + 255) / 256, 256, 0, stream>>>(bg_cnt, bg_pack, W + oDBG, Pn);
  kgather<false><<<512, 256, 0, stream>>>(bg_cnt, bg_pack, W + oDBG, W + oRBG, W + oABG, nullptr, Pn);

  // --- pert path (Pn rows, fp32) ---
  gemm64k<true, false, false, false, true><<<79, 256, 0, stream>>>(
      W + oAGO, W + oABG, W + oM1, W + oM2, W + oCcP, nullptr, nullptr, nullptr, 0, W + oM1B, W + oSP1, Pn);
  kfin<<<1, 64, 0, stream>>>(W + oSP1, mlp_g, mlp_bt, W + oAP1, W + oBP1, 64, 1.f / Pn);
  gemm64k<false, true, true, false, true><<<79, 256, 0, stream>>>(
      W + oM1B, nullptr, mlp_W + 4096, nullptr, mlp_b + 64, W + oAP1, W + oBP1, nullptr, 0, W + oM2B, W + oSP2, Pn);
  kfin<<<1, 64, 0, stream>>>(W + oSP2, mlp_g + 64, mlp_bt + 64, W + oAP2, W + oBP2, 64, 1.f / Pn);
  kemb<<<1, 256, 0, stream>>>(W + oM2B, W + oAP2, W + oBP2, pert_idx,
                              mlp_W + 16384, mlp_b + 256, mlp_g + 256, mlp_bt + 256, W + oEMB);

  // --- main N pipeline (MFMA bf16) ---
  // t1 = agg@M^T + Q[g]; stats S1
  gemm_mf<2, false, false, true><<<1250, 256, 0, stream>>>(
      (const u16*)buf0, Mbf, W + oZERO, nullptr, nullptr, W + oQ, (u16*)buf1, 64, 0, W + oS1, 64);
  kfin<<<1, 64, 0, stream>>>(W + oS1, mlp_g + 128, mlp_bt + 128, W + oA1, W + oB1, 64, 1.f / Nn);
  // t2 = relu(a1*t1+b1)@W11^T + b11; stats S2
  gemm_mf<2, true, false, false><<<1250, 256, 0, stream>>>(
      (const u16*)buf1, W11bf, mlp_b + 192, W + oA1, W + oB1, nullptr, (u16*)buf0, 64, 0, W + oS2, 64);
  kfin<<<1, 64, 0, stream>>>(W + oS2, mlp_g + 192, mlp_bt + 192, W + oA2, W + oB2, 64, 1.f / Nn);
  // stats of u = a2*t2+b2+emb[b]
  k7_kernel<<<512, 256, 0, stream>>>((const u16*)buf0, W + oA2, W + oB2, W + oEMB, W + oS3);
  kfinS3e2<<<1, 256, 0, stream>>>(W + oS3, bn_g + 64, bn_b + 64, W + oA2, W + oB2, W + oEMB,
                                  W + oAvec, W + oE2, 1.f / Nn);
  // r1 (two 64-col halves): base2 = relu(Avec*t2+e2[b]); r1 bf16 pitch 128
  gemm_mf<2, true, true, false><<<1250, 256, 0, stream>>>(
      (const u16*)buf0, W1bf, rec_b1, W + oAvec, W + oE2, nullptr, (u16*)buf1, 128, 0, W + oS4, 128);
  gemm_mf<2, true, true, false><<<1250, 256, 0, stream>>>(
      (const u16*)buf0, W1bf + 4096, rec_b1 + 64, W + oAvec, W + oE2, nullptr, (u16*)buf1, 128, 64, W + oS4 + 64, 128);
  kfin<<<2, 64, 0, stream>>>(W + oS4, rec_g1, rec_bt1, W + oA4, W + oB4, 128, 1.f / Nn);
  // r2 = relu(a4*r1+b4)@W2^T + b2; stats S5
  gemm_mf<4, true, false, false><<<1250, 256, 0, stream>>>(
      (const u16*)buf1, W2bf, rec_b2, W + oA4, W + oB4, nullptr, (u16*)buf0, 64, 0, W + oS5, 64);
  kfin<<<1, 64, 0, stream>>>(W + oS5, rec_g2, rec_bt2, W + oA5, W + oB5, 64, 1.f / Nn);
  k13_kernel<<<(Nn * 16 + 255) / 256, 256, 0, stream>>>((const u16*)buf0, W + oA5, W + oB5, indv_w1, indv_b1,
                                                        W + oW1, Nn);
  // cross-gene state
  kinitcg<<<8, 256, 0, stream>>>(cg_b1, W + oCGRAW);
  kcg1s<<<(Gn + 63) / 64, 256, 0, stream>>>(W + oW1, cg_W1, W + oCGRAW);
  kcg2<<<1, 256, 0, stream>>>(W + oCGRAW, cg_g1, cg_bt1, cg_W2, cg_b2, cg_g2, cg_bt2, W + oCG2);
  kfinal<<<(Gn + 63) / 64, 256, 0, stream>>>(W + oW1, W + oCG2, indv_w2, indv_b2, x, (float*)d_out);
}